// Round 3
// baseline (9780.892 us; speedup 1.0000x reference)
//
#include <hip/hip_runtime.h>
#include <cmath>

// Problem constants (fixed by the reference file)
#define B_ 1024
#define F_ 4096
#define V_ 20000
#define E_ 512
#define H_ 1024
#define L_ 20
#define D_ 4

typedef __bf16 bf16x8 __attribute__((ext_vector_type(8)));
typedef float  f32x4  __attribute__((ext_vector_type(4)));

#define BM 128
#define BN 128
#define BK 32
#define BKP 40   // padded LDS row: 40 bf16 = 80 B -> bank stride 20, 2-way max (free)

// ---------------------------------------------------------------------------
// Split-bf16 MFMA NT GEMM (general):
//   C[M,N] = A1[M,K1] @ W1[N,K1]^T (+ A2[M,K2] @ W2[N,K2]^T) (+ b1 + b2)
// 3 MFMAs per k-chunk (hi*hi + hi*lo + lo*hi) ~ fp32 accuracy.
// M % 128 == 0, K % 32 == 0. Grid: x = M/128 (fast -> W tiles reused in L2),
// y = ceil(N/128).
// ---------------------------------------------------------------------------
__global__ __launch_bounds__(256, 2) void gemm_nt_split(
    const float* __restrict__ A1, const float* __restrict__ W1, int K1,
    const float* __restrict__ A2, const float* __restrict__ W2, int K2,
    const float* __restrict__ b1, const float* __restrict__ b2,
    float* __restrict__ C, int M, int N)
{
    __shared__ __align__(16) __bf16 As_hi[BM][BKP];
    __shared__ __align__(16) __bf16 As_lo[BM][BKP];
    __shared__ __align__(16) __bf16 Ws_hi[BN][BKP];
    __shared__ __align__(16) __bf16 Ws_lo[BN][BKP];

    const int tid  = threadIdx.x;
    const int bm   = blockIdx.x * BM;   // M is the fast grid axis
    const int bn   = blockIdx.y * BN;
    const int srow = tid >> 1;          // 0..127
    const int scol = (tid & 1) * 16;    // 0 or 16
    const int lane = tid & 63;
    const int wv   = tid >> 6;
    const int wm   = (wv & 1) * 64;
    const int wn   = (wv >> 1) * 64;
    const int fm   = lane & 15;
    const int fq   = lane >> 4;

    const bool wok = (bn + srow) < N;

    f32x4 acc[4][4];
#pragma unroll
    for (int i = 0; i < 4; ++i)
#pragma unroll
        for (int j = 0; j < 4; ++j) acc[i][j] = (f32x4){0.f, 0.f, 0.f, 0.f};

#pragma unroll 1
    for (int s = 0; s < 2; ++s) {
        const float* A = s ? A2 : A1;
        const float* W = s ? W2 : W1;
        const int    K = s ? K2 : K1;
        if (!A) continue;
        const float* Arow = A + (size_t)(bm + srow) * K;
        const float* Wrow = W + (size_t)(bn + srow) * K;

        for (int k0 = 0; k0 < K; k0 += BK) {
            float av[16], wvv[16];
            const float* ap = Arow + k0 + scol;
            *(float4*)&av[0]   = *(const float4*)(ap + 0);
            *(float4*)&av[4]   = *(const float4*)(ap + 4);
            *(float4*)&av[8]   = *(const float4*)(ap + 8);
            *(float4*)&av[12]  = *(const float4*)(ap + 12);
            if (wok) {
                const float* wp = Wrow + k0 + scol;
                *(float4*)&wvv[0]  = *(const float4*)(wp + 0);
                *(float4*)&wvv[4]  = *(const float4*)(wp + 4);
                *(float4*)&wvv[8]  = *(const float4*)(wp + 8);
                *(float4*)&wvv[12] = *(const float4*)(wp + 12);
            } else {
#pragma unroll
                for (int v = 0; v < 16; ++v) wvv[v] = 0.f;
            }
            __syncthreads();
#pragma unroll
            for (int u = 0; u < 16; u += 8) {
                bf16x8 hh, ll;
#pragma unroll
                for (int v = 0; v < 8; ++v) {
                    float x = av[u + v];
                    __bf16 h = (__bf16)x;
                    hh[v] = h;
                    ll[v] = (__bf16)(x - (float)h);
                }
                *(bf16x8*)&As_hi[srow][scol + u] = hh;
                *(bf16x8*)&As_lo[srow][scol + u] = ll;
            }
#pragma unroll
            for (int u = 0; u < 16; u += 8) {
                bf16x8 hh, ll;
#pragma unroll
                for (int v = 0; v < 8; ++v) {
                    float x = wvv[u + v];
                    __bf16 h = (__bf16)x;
                    hh[v] = h;
                    ll[v] = (__bf16)(x - (float)h);
                }
                *(bf16x8*)&Ws_hi[srow][scol + u] = hh;
                *(bf16x8*)&Ws_lo[srow][scol + u] = ll;
            }
            __syncthreads();

            bf16x8 ah[4], al[4];
#pragma unroll
            for (int i = 0; i < 4; ++i) {
                ah[i] = *(const bf16x8*)&As_hi[wm + i * 16 + fm][fq * 8];
                al[i] = *(const bf16x8*)&As_lo[wm + i * 16 + fm][fq * 8];
            }
#pragma unroll
            for (int j = 0; j < 4; ++j) {
                bf16x8 bh = *(const bf16x8*)&Ws_hi[wn + j * 16 + fm][fq * 8];
                bf16x8 bl = *(const bf16x8*)&Ws_lo[wn + j * 16 + fm][fq * 8];
#pragma unroll
                for (int i = 0; i < 4; ++i) {
                    acc[i][j] = __builtin_amdgcn_mfma_f32_16x16x32_bf16(
                        al[i], bh, acc[i][j], 0, 0, 0);
                    acc[i][j] = __builtin_amdgcn_mfma_f32_16x16x32_bf16(
                        ah[i], bl, acc[i][j], 0, 0, 0);
                    acc[i][j] = __builtin_amdgcn_mfma_f32_16x16x32_bf16(
                        ah[i], bh, acc[i][j], 0, 0, 0);
                }
            }
        }
    }

    // epilogue: C/D layout col = lane&15, row = quad*4 + reg
#pragma unroll
    for (int j = 0; j < 4; ++j) {
        int col = bn + wn + j * 16 + fm;
        if (col >= N) continue;
        float badd = (b1 ? b1[col] : 0.f) + (b2 ? b2[col] : 0.f);
#pragma unroll
        for (int i = 0; i < 4; ++i) {
            int row0 = bm + wm + i * 16 + fq * 4;
            f32x4 v = acc[i][j];
#pragma unroll
            for (int r = 0; r < 4; ++r)
                C[(size_t)(row0 + r) * N + col] = v[r] + badd;
        }
    }
}

// ---------------------------------------------------------------------------
// Logits GEMM with fused argmax + logsumexp epilogue. No C write.
// A[B_,H_] @ W[N,H_]^T + bias, tile 128x256, 4 waves of 64x128.
// Per (row, n-block, wave-half) partial: float4(max, idx_bits, lse_m, lse_s)
// part has NPB = 2*ceil(N/256) entries per row (one per wave-half).
// Grid: x = B_/128 (fast), y = ceil(N/256).
// ---------------------------------------------------------------------------
#define LBN 256

__global__ __launch_bounds__(256, 2) void gemm_logits_fused(
    const float* __restrict__ A, const float* __restrict__ W,
    const float* __restrict__ bias, float4* __restrict__ part,
    int N, int NPB)
{
    __shared__ __align__(16) __bf16 As_hi[BM][BKP];
    __shared__ __align__(16) __bf16 As_lo[BM][BKP];
    __shared__ __align__(16) __bf16 Ws_hi[LBN][BKP];
    __shared__ __align__(16) __bf16 Ws_lo[LBN][BKP];

    const int tid  = threadIdx.x;
    const int bm   = blockIdx.x * BM;
    const int bn   = blockIdx.y * LBN;
    const int srow = tid >> 1;
    const int scol = (tid & 1) * 16;
    const int lane = tid & 63;
    const int wv   = tid >> 6;
    const int wm   = (wv & 1) * 64;
    const int wn   = (wv >> 1) * 128;   // wave-half: 0 or 1 -> cols +0 / +128
    const int fm   = lane & 15;
    const int fq   = lane >> 4;

    f32x4 acc[4][8];
#pragma unroll
    for (int i = 0; i < 4; ++i)
#pragma unroll
        for (int j = 0; j < 8; ++j) acc[i][j] = (f32x4){0.f, 0.f, 0.f, 0.f};

    const float* Arow  = A + (size_t)(bm + srow) * H_;
    const int wr0 = bn + srow, wr1 = bn + 128 + srow;
    const float* Wrow0 = W + (size_t)wr0 * H_;
    const float* Wrow1 = W + (size_t)wr1 * H_;
    const bool wok0 = wr0 < N, wok1 = wr1 < N;

    for (int k0 = 0; k0 < H_; k0 += BK) {
        float av[16], w0[16], w1[16];
        const float* ap = Arow + k0 + scol;
        *(float4*)&av[0]  = *(const float4*)(ap + 0);
        *(float4*)&av[4]  = *(const float4*)(ap + 4);
        *(float4*)&av[8]  = *(const float4*)(ap + 8);
        *(float4*)&av[12] = *(const float4*)(ap + 12);
        if (wok0) {
            const float* wp = Wrow0 + k0 + scol;
            *(float4*)&w0[0]  = *(const float4*)(wp + 0);
            *(float4*)&w0[4]  = *(const float4*)(wp + 4);
            *(float4*)&w0[8]  = *(const float4*)(wp + 8);
            *(float4*)&w0[12] = *(const float4*)(wp + 12);
        } else {
#pragma unroll
            for (int v = 0; v < 16; ++v) w0[v] = 0.f;
        }
        if (wok1) {
            const float* wp = Wrow1 + k0 + scol;
            *(float4*)&w1[0]  = *(const float4*)(wp + 0);
            *(float4*)&w1[4]  = *(const float4*)(wp + 4);
            *(float4*)&w1[8]  = *(const float4*)(wp + 8);
            *(float4*)&w1[12] = *(const float4*)(wp + 12);
        } else {
#pragma unroll
            for (int v = 0; v < 16; ++v) w1[v] = 0.f;
        }
        __syncthreads();
#pragma unroll
        for (int u = 0; u < 16; u += 8) {
            bf16x8 hh, ll;
#pragma unroll
            for (int v = 0; v < 8; ++v) {
                float x = av[u + v];
                __bf16 h = (__bf16)x;
                hh[v] = h; ll[v] = (__bf16)(x - (float)h);
            }
            *(bf16x8*)&As_hi[srow][scol + u] = hh;
            *(bf16x8*)&As_lo[srow][scol + u] = ll;
        }
#pragma unroll
        for (int u = 0; u < 16; u += 8) {
            bf16x8 hh, ll;
#pragma unroll
            for (int v = 0; v < 8; ++v) {
                float x = w0[u + v];
                __bf16 h = (__bf16)x;
                hh[v] = h; ll[v] = (__bf16)(x - (float)h);
            }
            *(bf16x8*)&Ws_hi[srow][scol + u] = hh;
            *(bf16x8*)&Ws_lo[srow][scol + u] = ll;
        }
#pragma unroll
        for (int u = 0; u < 16; u += 8) {
            bf16x8 hh, ll;
#pragma unroll
            for (int v = 0; v < 8; ++v) {
                float x = w1[u + v];
                __bf16 h = (__bf16)x;
                hh[v] = h; ll[v] = (__bf16)(x - (float)h);
            }
            *(bf16x8*)&Ws_hi[128 + srow][scol + u] = hh;
            *(bf16x8*)&Ws_lo[128 + srow][scol + u] = ll;
        }
        __syncthreads();

        bf16x8 ah[4], al[4];
#pragma unroll
        for (int i = 0; i < 4; ++i) {
            ah[i] = *(const bf16x8*)&As_hi[wm + i * 16 + fm][fq * 8];
            al[i] = *(const bf16x8*)&As_lo[wm + i * 16 + fm][fq * 8];
        }
#pragma unroll
        for (int j = 0; j < 8; ++j) {
            bf16x8 bh = *(const bf16x8*)&Ws_hi[wn + j * 16 + fm][fq * 8];
            bf16x8 bl = *(const bf16x8*)&Ws_lo[wn + j * 16 + fm][fq * 8];
#pragma unroll
            for (int i = 0; i < 4; ++i) {
                acc[i][j] = __builtin_amdgcn_mfma_f32_16x16x32_bf16(
                    al[i], bh, acc[i][j], 0, 0, 0);
                acc[i][j] = __builtin_amdgcn_mfma_f32_16x16x32_bf16(
                    ah[i], bl, acc[i][j], 0, 0, 0);
                acc[i][j] = __builtin_amdgcn_mfma_f32_16x16x32_bf16(
                    ah[i], bh, acc[i][j], 0, 0, 0);
            }
        }
    }

    // fused epilogue: per-row argmax (first-occurrence) + online LSE over
    // this wave's 128 columns; butterfly across the 16-lane fm group.
    const int pbase = blockIdx.y * 2 + (wv >> 1);
#pragma unroll
    for (int i = 0; i < 4; ++i) {
#pragma unroll
        for (int r = 0; r < 4; ++r) {
            int row = bm + wm + i * 16 + fq * 4 + r;
            float mx = -INFINITY; int mi = 0x7fffffff;
            float lm = -INFINITY, lss = 0.f;
#pragma unroll
            for (int j = 0; j < 8; ++j) {
                int col = bn + wn + j * 16 + fm;
                if (col < N) {
                    float v = acc[i][j][r] + bias[col];
                    if (v > mx) { mx = v; mi = col; }
                    if (v > lm) { lss = lss * expf(lm - v) + 1.f; lm = v; }
                    else lss += expf(v - lm);
                }
            }
#pragma unroll
            for (int d = 1; d < 16; d <<= 1) {
                float omx = __shfl_xor(mx, d);
                int   omi = __shfl_xor(mi, d);
                float olm = __shfl_xor(lm, d);
                float ols = __shfl_xor(lss, d);
                if (omx > mx || (omx == mx && omi < mi)) { mx = omx; mi = omi; }
                if (olm > lm) { lss = ols + lss * expf(lm - olm); lm = olm; }
                else if (olm > -INFINITY) lss += ols * expf(olm - lm);
            }
            if (fm == 0)
                part[(size_t)row * NPB + pbase] =
                    make_float4(mx, __int_as_float(mi), lm, lss);
        }
    }
}

// ---------------------------------------------------------------------------
// Combine per-row partials -> greedy token + logprob of that token.
// Grid: B_, block: 64 (one wave).
// ---------------------------------------------------------------------------
__global__ __launch_bounds__(64) void combine_rows(
    const float4* __restrict__ part, int NPB,
    int* __restrict__ tok, float* __restrict__ lp)
{
    int row = blockIdx.x, tid = threadIdx.x;
    float mx = -INFINITY; int mi = 0x7fffffff;
    float lm = -INFINITY, lss = 0.f;
    for (int p = tid; p < NPB; p += 64) {
        float4 q = part[(size_t)row * NPB + p];
        int qi = __float_as_int(q.y);
        if (q.x > mx || (q.x == mx && qi < mi)) { mx = q.x; mi = qi; }
        if (q.z > lm) { lss = q.w + lss * expf(lm - q.z); lm = q.z; }
        else if (q.z > -INFINITY) lss += q.w * expf(q.z - lm);
    }
#pragma unroll
    for (int d = 1; d < 64; d <<= 1) {
        float omx = __shfl_xor(mx, d);
        int   omi = __shfl_xor(mi, d);
        float olm = __shfl_xor(lm, d);
        float ols = __shfl_xor(lss, d);
        if (omx > mx || (omx == mx && omi < mi)) { mx = omx; mi = omi; }
        if (olm > lm) { lss = ols + lss * expf(lm - olm); lm = olm; }
        else if (olm > -INFINITY) lss += ols * expf(olm - lm);
    }
    if (tid == 0) {
        tok[row] = mi;
        lp[row] = mx - (lm + logf(lss));
    }
}

// ---------------------------------------------------------------------------
// LSTM pointwise
// ---------------------------------------------------------------------------
__global__ __launch_bounds__(256) void lstm_pointwise(
    const float* __restrict__ gates, float* __restrict__ c, float* __restrict__ h)
{
    int i = blockIdx.x * blockDim.x + threadIdx.x;
    if (i >= B_ * H_) return;
    int b = i / H_, k = i % H_;
    const float* g = gates + (size_t)b * 4 * H_;
    float gi = g[k], gf = g[H_ + k], gg = g[2 * H_ + k], go = g[3 * H_ + k];
    float si = 1.f / (1.f + expf(-gi));
    float sf = 1.f / (1.f + expf(-gf));
    float so = 1.f / (1.f + expf(-go));
    float cn = sf * c[i] + si * tanhf(gg);
    c[i] = cn;
    h[i] = so * tanhf(cn);
}

// ---------------------------------------------------------------------------
// Embedding gathers
// ---------------------------------------------------------------------------
__global__ __launch_bounds__(128) void gather_emb(
    const float* __restrict__ emb, const int* __restrict__ tok,
    float* __restrict__ out)
{
    int b = blockIdx.x;
    int t = tok[b];
    const float4* src = (const float4*)(emb + (size_t)t * E_);
    float4* dst = (float4*)(out + (size_t)b * E_);
    for (int e = threadIdx.x; e < E_ / 4; e += blockDim.x) dst[e] = src[e];
}

__global__ __launch_bounds__(128) void broadcast_emb(
    const float* __restrict__ emb, const int* __restrict__ sidx,
    float* __restrict__ out)
{
    int b = blockIdx.x;
    int t = sidx[0];
    const float4* src = (const float4*)(emb + (size_t)t * E_);
    float4* dst = (float4*)(out + (size_t)b * E_);
    for (int e = threadIdx.x; e < E_ / 4; e += blockDim.x) dst[e] = src[e];
}

__global__ __launch_bounds__(256) void zero_f32(float* __restrict__ p, int n)
{
    int i = blockIdx.x * blockDim.x + threadIdx.x;
    if (i < n) p[i] = 0.f;
}

// ---------------------------------------------------------------------------
// Loss rows + finalize
// ---------------------------------------------------------------------------
__global__ __launch_bounds__(256) void loss_rows(
    const float* __restrict__ sc, const float* __restrict__ lp,
    float* __restrict__ loss_part, float* __restrict__ acc_flag)
{
    int i = blockIdx.x; int tid = threadIdx.x;
    const float* tsrow = sc + (size_t)i * B_;
    float lsum = 0.f, tps = 0.f;
    float dps[4] = {0.f, 0.f, 0.f, 0.f};
    for (int j = tid; j < B_; j += 256) {
        float tsv = tsrow[j];
        float hv = 0.f;
#pragma unroll
        for (int d = 0; d < 4; ++d) {
            float dv = sc[((size_t)(1 + d) * B_ + i) * B_ + j];
            float t = 1.f - tsv + dv;
            hv += (t > 0.f) ? t : 0.f;
            dps[d] += expf(dv);
        }
        lsum += hv * lp[j];
        tps += expf(tsv);
    }
    __shared__ float red[6][256];
    red[0][tid] = lsum; red[1][tid] = tps;
    red[2][tid] = dps[0]; red[3][tid] = dps[1];
    red[4][tid] = dps[2]; red[5][tid] = dps[3];
    __syncthreads();
    for (int s = 128; s > 0; s >>= 1) {
        if (tid < s) {
#pragma unroll
            for (int q = 0; q < 6; ++q) red[q][tid] += red[q][tid + s];
        }
        __syncthreads();
    }
    if (tid == 0) {
        loss_part[i] = -red[0][0];
        float tp = red[1][0];
        float mx = fmaxf(fmaxf(red[2][0], red[3][0]), fmaxf(red[4][0], red[5][0]));
        acc_flag[i] = (tp >= mx) ? 1.f : 0.f;
    }
}

__global__ __launch_bounds__(256) void finalize_k(
    const float* __restrict__ loss_part, const float* __restrict__ acc_flag,
    float* __restrict__ out)
{
    int tid = threadIdx.x;
    float ls = 0.f, ac = 0.f;
    for (int i = tid; i < B_; i += 256) { ls += loss_part[i]; ac += acc_flag[i]; }
    __shared__ float s1[256], s2[256];
    s1[tid] = ls; s2[tid] = ac;
    __syncthreads();
    for (int s = 128; s > 0; s >>= 1) {
        if (tid < s) { s1[tid] += s1[tid + s]; s2[tid] += s2[tid + s]; }
        __syncthreads();
    }
    if (tid == 0) {
        out[0] = s1[0] / ((float)B_ * (float)B_);
        out[1] = s2[0] / (float)B_;
    }
}

// ---------------------------------------------------------------------------
// Host launcher
// ---------------------------------------------------------------------------
extern "C" void kernel_launch(void* const* d_in, const int* in_sizes, int n_in,
                              void* d_out, int out_size, void* d_ws, size_t ws_size,
                              hipStream_t stream)
{
    const float* target    = (const float*)d_in[0];
    const float* distract  = (const float*)d_in[1];
    const int*   start_tok = (const int*)d_in[2];
    const float* emb_s   = (const float*)d_in[4];
    const float* Wih_s   = (const float*)d_in[5];
    const float* Whh_s   = (const float*)d_in[6];
    const float* bih_s   = (const float*)d_in[7];
    const float* bhh_s   = (const float*)d_in[8];
    const float* aff_s_W = (const float*)d_in[9];
    const float* aff_s_b = (const float*)d_in[10];
    const float* probs_W = (const float*)d_in[11];
    const float* probs_b = (const float*)d_in[12];
    const float* emb_r   = (const float*)d_in[13];
    const float* Wih_r   = (const float*)d_in[14];
    const float* Whh_r   = (const float*)d_in[15];
    const float* bih_r   = (const float*)d_in[16];
    const float* bhh_r   = (const float*)d_in[17];
    const float* aff_r_W = (const float*)d_in[18];
    const float* aff_r_b = (const float*)d_in[19];

    float* ws = (float*)d_ws;
    const size_t OFF_HS     = 0;                 // [B,H]
    const size_t OFF_CS     = 1048576;           // [B,H]
    const size_t OFF_WE     = 2097152;           // [B,E]
    const size_t OFF_GATES  = 2621440;           // [B,4H]
    const size_t OFF_HR     = 6815744;           // [B,H]
    const size_t OFF_CR     = 7864320;           // [B,H]
    const size_t OFF_LP     = 8912896;           // [B]
    const size_t OFF_LOSSP  = 8916992;           // [B]
    const size_t OFF_ACCF   = 8921088;           // [B]
    const size_t OFF_MSG    = 8925184;           // int [L,B]
    const size_t OFF_PART   = 9437184;           // float4 [B, NPB]
    const size_t OFF_R      = 10485760;          // [B,F]
    const size_t OFF_SC     = 14680064;          // [5,B,B]

    float* h_s    = ws + OFF_HS;
    float* c_s    = ws + OFF_CS;
    float* w_e    = ws + OFF_WE;
    float* gates  = ws + OFF_GATES;
    float* h_r    = ws + OFF_HR;
    float* c_r    = ws + OFF_CR;
    float* lp     = ws + OFF_LP;
    float* lossp  = ws + OFF_LOSSP;
    float* accf   = ws + OFF_ACCF;
    int*   msg    = (int*)(ws + OFF_MSG);
    float4* part  = (float4*)(ws + OFF_PART);
    float* r_buf  = ws + OFF_R;
    float* sc     = ws + OFF_SC;

    const int NPB = 2 * ((V_ + LBN - 1) / LBN);  // 158 partials per row

    auto gemm = [&](const float* A1, const float* W1, int K1,
                    const float* A2, const float* W2, int K2,
                    const float* b1, const float* b2,
                    float* C, int M, int N) {
        dim3 grid(M / BM, (N + BN - 1) / BN);
        gemm_nt_split<<<grid, dim3(256), 0, stream>>>(A1, W1, K1, A2, W2, K2,
                                                      b1, b2, C, M, N);
    };

    // ---- Sender ----
    gemm(target, aff_s_W, F_, nullptr, nullptr, 0, aff_s_b, nullptr, h_s, B_, H_);
    zero_f32<<<(B_ * H_ + 255) / 256, 256, 0, stream>>>(c_s, B_ * H_);
    broadcast_emb<<<B_, 128, 0, stream>>>(emb_s, start_tok, w_e);

    dim3 lgrid(B_ / BM, (V_ + LBN - 1) / LBN);
    for (int t = 0; t < L_; ++t) {
        gemm(w_e, Wih_s, E_, h_s, Whh_s, H_, bih_s, bhh_s, gates, B_, 4 * H_);
        lstm_pointwise<<<(B_ * H_ + 255) / 256, 256, 0, stream>>>(gates, c_s, h_s);
        gemm_logits_fused<<<lgrid, dim3(256), 0, stream>>>(
            h_s, probs_W, probs_b, part, V_, NPB);
        combine_rows<<<B_, 64, 0, stream>>>(part, NPB, msg + (size_t)t * B_, lp);
        if (t < L_ - 1)
            gather_emb<<<B_, 128, 0, stream>>>(emb_s, msg + (size_t)t * B_, w_e);
    }

    // ---- Receiver ----
    zero_f32<<<(B_ * H_ + 255) / 256, 256, 0, stream>>>(h_r, B_ * H_);
    zero_f32<<<(B_ * H_ + 255) / 256, 256, 0, stream>>>(c_r, B_ * H_);
    for (int t = 0; t < L_; ++t) {
        gather_emb<<<B_, 128, 0, stream>>>(emb_r, msg + (size_t)t * B_, w_e);
        gemm(w_e, Wih_r, E_, h_r, Whh_r, H_, bih_r, bhh_r, gates, B_, 4 * H_);
        lstm_pointwise<<<(B_ * H_ + 255) / 256, 256, 0, stream>>>(gates, c_r, h_r);
    }

    // r = h_r @ aff_r_W.T + aff_r_b   [B,F]
    gemm(h_r, aff_r_W, H_, nullptr, nullptr, 0, aff_r_b, nullptr, r_buf, B_, F_);

    // scores
    gemm(target, r_buf, F_, nullptr, nullptr, 0, nullptr, nullptr, sc, B_, B_);
    gemm(distract, r_buf, F_, nullptr, nullptr, 0, nullptr, nullptr,
         sc + (size_t)B_ * B_, D_ * B_, B_);

    loss_rows<<<B_, 256, 0, stream>>>(sc, lp, lossp, accf);
    finalize_k<<<1, 256, 0, stream>>>(lossp, accf, (float*)d_out);
}